// Round 12
// baseline (179.575 us; speedup 1.0000x reference)
//
#include <hip/hip_runtime.h>

#define HH 299
#define WW 299
#define HW (HH * WW)
#define BORDER 3
#define NT 320
#define RPB 4
#define CHUNKS 75            // ceil(299/4)
#define INV299 (1.0f / 299.0f)

typedef float f4 __attribute__((ext_vector_type(4)));
typedef f4 __attribute__((aligned(4))) f4a;   // 4B-aligned float4 load/store

__global__ __launch_bounds__(NT) void crop_resize_kernel(
    const float* __restrict__ x,   // (S, 3, H, W)
    const int*   __restrict__ f,   // (S, G, 4)
    float*       __restrict__ out, // (S, G, 3, H, W)
    int G)
{
    __shared__ float sV[RPB][3][304];   // fused vertical rows, 14.6 KB
    __shared__ float sFy[304];          // per-column interp weight
    __shared__ int   sBy[304];          // per-column base index

    // Bijective XCD swizzle (grid = 38400 = 8 * 4800).
    int cpx = (int)(gridDim.x >> 3);
    int hb  = blockIdx.x;
    int blk = (hb & 7) * cpx + (hb >> 3);

    int sg = blk / CHUNKS;               // crop index si*G + gi
    int r0 = (blk - sg * CHUNKS) * RPB;  // first output row of this block
    int si = sg / G;

    const int* box = f + (sg << 2);
    int tlx = max(box[0] - BORDER, 0);
    int tly = max(box[1] - BORDER, 0);
    int hc  = min(box[2] + BORDER, HH - 1) - tlx;
    int wc  = min(box[3] + BORDER, WW - 1) - tly;

    int t = threadIdx.x;
    const float* img = x + si * 3 * HW;

    // Row (x-axis) coords for RPB rows — block-uniform, division-free.
    float hstep = (float)hc * INV299;
    int   gxb[RPB]; float fxa[RPB];
    #pragma unroll
    for (int r = 0; r < RPB; ++r) {
        int row = min(r0 + r, HH - 1);
        float sx = fmaf((float)row + 0.5f, hstep, -0.5f);
        sx = fminf(fmaxf(sx, 0.0f), (float)hc - 1.0f);
        int bx = max(min((int)floorf(sx), hc - 2), 0);
        fxa[r] = sx - (float)bx;
        gxb[r] = tlx + bx;
    }

    // Column (y-axis) coord table — once per block, into LDS.
    if (t < WW) {
        float sy = fmaf((float)t + 0.5f, (float)wc * INV299, -0.5f);
        sy = fminf(fmaxf(sy, 0.0f), (float)wc - 1.0f);
        int by = max(min((int)floorf(sy), wc - 2), 0);
        sBy[t] = by;
        sFy[t] = sy - (float)by;
    }

    // Staging: unit u in [0, RPB*228): r = u/228, ch = (u%228)/76, quad q.
    #pragma unroll
    for (int pass = 0; pass < 3; ++pass) {
        int u = t + pass * NT;
        if (u < RPB * 228) {
            int r  = u / 228;
            int m  = u - r * 228;
            int ch = m / 76;
            int q  = (m - ch * 76) << 2;
            if (q < wc) {
                int c = min(q, wc - 3);          // 16B read stays inside row
                const float* p = img + ch * HW + gxb[r] * WW + tly + c;
                f4 a = *(const f4a*)p;           // source row bx
                f4 b = *(const f4a*)(p + WW);    // source row bx+1
                float fr = fxa[r], om = 1.0f - fr;
                sV[r][ch][c + 0] = fmaf(a.x, om, b.x * fr);
                sV[r][ch][c + 1] = fmaf(a.y, om, b.y * fr);
                sV[r][ch][c + 2] = fmaf(a.z, om, b.z * fr);
                sV[r][ch][c + 3] = fmaf(a.w, om, b.w * fr);
            }
        }
    }
    __syncthreads();

    // Output: store-units (r, ch, quad-of-4-columns) -> ONE dwordx4 store.
    // 75 quads cover cols 0..298 (last quad rebased to 295, dup col benign).
    #pragma unroll
    for (int pass = 0; pass < 3; ++pass) {
        int u = t + pass * NT;
        if (u < RPB * 225) {
            int r  = u / 225;
            int m  = u - r * 225;
            int ch = m / 75;
            int q  = m - ch * 75;
            int c  = min(q << 2, WW - 4);        // 0,4,...,292,295
            int row = r0 + r;
            if (row < HH) {
                const float* v = &sV[r][ch][0];
                f4 o;
                {   int by = sBy[c];     float fy = sFy[c];
                    o.x = fmaf(v[by], 1.0f - fy, v[by + 1] * fy); }
                {   int by = sBy[c + 1]; float fy = sFy[c + 1];
                    o.y = fmaf(v[by], 1.0f - fy, v[by + 1] * fy); }
                {   int by = sBy[c + 2]; float fy = sFy[c + 2];
                    o.z = fmaf(v[by], 1.0f - fy, v[by + 1] * fy); }
                {   int by = sBy[c + 3]; float fy = sFy[c + 3];
                    o.w = fmaf(v[by], 1.0f - fy, v[by + 1] * fy); }
                *(f4a*)(out + (size_t)sg * 3 * HW + ch * HW + row * WW + c) = o;
            }
        }
    }
}

extern "C" void kernel_launch(void* const* d_in, const int* in_sizes, int n_in,
                              void* d_out, int out_size, void* d_ws, size_t ws_size,
                              hipStream_t stream) {
    const float* x = (const float*)d_in[0];
    const int*   f = (const int*)d_in[1];
    float* out = (float*)d_out;

    int S = in_sizes[0] / (3 * HW);   // 32
    int G = in_sizes[1] / (S * 4);    // 16

    dim3 grid((unsigned)(S * G * CHUNKS));  // 38400 = 8 * 4800
    dim3 block(NT);
    crop_resize_kernel<<<grid, block, 0, stream>>>(x, f, out, G);
}